// Round 4
// baseline (393.021 us; speedup 1.0000x reference)
//
#include <hip/hip_runtime.h>
#include <stdint.h>

// Problem constants (fixed by setup_inputs): B=2, C=32, H=W=D=96, N=30000
#define HWD 884736ull          // 96*96*96
#define NV 30000               // vertices per batch
#define AST 1032               // LDS A-tile row stride (shorts): 2064B

typedef __attribute__((ext_vector_type(8))) __bf16 bf16x8;
typedef __attribute__((ext_vector_type(4))) float f32x4;
typedef __attribute__((ext_vector_type(2))) float f32x2;
typedef __attribute__((ext_vector_type(4))) unsigned int uint4v;

__device__ __forceinline__ unsigned short f2bf(float f) {
    union { float f; unsigned int u; } v; v.f = f;
    unsigned int u = v.u;
    return (unsigned short)((u + 0x7FFFu + ((u >> 16) & 1u)) >> 16);  // RNE (prep only)
}

// Native HW bf16 convert (RNE) -> compiler emits v_cvt_pk_bf16_f32 pairs
__device__ __forceinline__ unsigned short bfc(float f) {
    __bf16 h = (__bf16)f;
    unsigned short u;
    __builtin_memcpy(&u, &h, 2);
    return u;
}

// Unpack a uint holding two adjacent-channel bf16 values -> float2
__device__ __forceinline__ f32x2 up2(unsigned int u) {
    union { unsigned int u; float f; } lo, hi;
    lo.u = u << 16;
    hi.u = u & 0xFFFF0000u;
    f32x2 r; r.x = lo.f; r.y = hi.f;
    return r;
}

// Per-axis folded 4-wide window weights (x and y axes).
__device__ __forceinline__ void axis_setup(float coord, float sc, int& wstart, float w[3][4]) {
    int i0[3], i1[3];
    float fr[3];
#pragma unroll
    for (int a = 0; a < 3; ++a) {
        float g = coord + (float)(a - 1) * sc;
        float ix = (g + 1.0f) * 0.5f * 95.0f;
        ix = fminf(fmaxf(ix, 0.0f), 95.0f);
        float fl = floorf(ix);
        int x0 = (int)fl;
        i0[a] = x0;
        i1[a] = min(x0 + 1, 95);
        fr[a] = ix - fl;
    }
    int ws = min(max(i0[1] - 1, 0), 92);
    wstart = ws;
#pragma unroll
    for (int a = 0; a < 3; ++a) {
        int d0 = min(max(i0[a] - ws, 0), 3);
        int d1 = min(max(i1[a] - ws, 0), 3);
        float f1 = fr[a], f0 = 1.0f - f1;
#pragma unroll
        for (int j = 0; j < 4; ++j)
            w[a][j] = (d0 == j ? f0 : 0.0f) + (d1 == j ? f1 : 0.0f);
    }
}

// z-axis: expose the <=2 nonzero taps per shift g directly (trilinear structure):
// tap indices dz[g][0..1] (relative to window start) and weights fzw[g][0..1].
// Iterating (d0 with 1-fr) then (d1 with fr) is bit-identical to the folded form.
__device__ __forceinline__ void axis_setup_z(float coord, float sc, int& wstart,
                                             int dz[3][2], float fzw[3][2]) {
    int i0[3], i1[3];
    float fr[3];
#pragma unroll
    for (int a = 0; a < 3; ++a) {
        float g = coord + (float)(a - 1) * sc;
        float ix = (g + 1.0f) * 0.5f * 95.0f;
        ix = fminf(fmaxf(ix, 0.0f), 95.0f);
        float fl = floorf(ix);
        int x0 = (int)fl;
        i0[a] = x0;
        i1[a] = min(x0 + 1, 95);
        fr[a] = ix - fl;
    }
    int ws = min(max(i0[1] - 1, 0), 92);
    wstart = ws;
#pragma unroll
    for (int a = 0; a < 3; ++a) {
        dz[a][0] = min(max(i0[a] - ws, 0), 3);
        dz[a][1] = min(max(i1[a] - ws, 0), 3);
        fzw[a][0] = 1.0f - fr[a];
        fzw[a][1] = fr[a];
    }
}

// Pack conv_w (32,32,1,27) fp32 -> bf16 B-fragments for mfma_f32_16x16x32_bf16.
// Layout (verified): element j of wp[(s*2+t)*64 + lane] is
// B[k = s*32 + (lane>>4)*8 + j][o = t*16 + (lane&15)]
__global__ __launch_bounds__(256) void prep_kernel(const float* __restrict__ cw,
                                                   unsigned short* __restrict__ Wp) {
    int gid = blockIdx.x * 256 + threadIdx.x;  // 0..32767
    int j = gid & 7;
    int l = (gid >> 3) & 63;
    int t = (gid >> 9) & 1;
    int s = gid >> 10;
    int kk = ((l >> 4) & 3) * 8 + j;
    int o = t * 16 + (l & 15);
    float v = 0.0f;
    if (kk < 27) v = cw[(size_t)o * 864 + s * 27 + kk];
    Wp[gid] = f2bf(v);
}

// (B,C,H,W,D) fp32 -> (B,H,W,D,C) bf16, LDS-staged for wide coalesced IO.
// (unchanged — near its BW floor)
__global__ __launch_bounds__(256) void transpose_kernel(const float* __restrict__ vox,
                                                        unsigned short* __restrict__ voxT) {
    __shared__ unsigned short T[192 * 40];     // 15.4 KB
    int blk = blockIdx.x;                      // 0..9215 encodes (b, z, y2)
    int tid = threadIdx.x;
    int b = blk / 4608;
    int zy = blk - b * 4608;                   // z*48 + y2
    const float* src = vox + (size_t)b * 32 * HWD + (size_t)zy * 192;
    int c = tid >> 3;                          // 0..31
    int xs = tid & 7;                          // x4 slot within 8-lane group
    const float* srcc = src + (size_t)c * HWD;
#pragma unroll
    for (int i = 0; i < 6; ++i) {
        int x4 = xs + 8 * i;                   // 0..47
        f32x4 v = *(const f32x4*)(srcc + x4 * 4);
#pragma unroll
        for (int k = 0; k < 4; ++k)
            T[(x4 * 4 + k) * 40 + c] = bfc(v[k]);
    }
    __syncthreads();
    unsigned short* dst = voxT + (size_t)blk * 6144;
#pragma unroll
    for (int i = 0; i < 3; ++i) {
        int q = i * 256 + tid;                 // 0..767 (16B chunks)
        int x = q >> 2;
        int cg = (q & 3) * 8;
        uint4v val = *(const uint4v*)&T[x * 40 + cg];
        *(uint4v*)(dst + q * 8) = val;
    }
}

// Fused sample + GEMM, g-outer restructure for register pressure.
// Block = 256 threads = 16 vertices x 16 channel-pairs. Per z-shift g (3 passes)
// only the <=2 contributing z-slabs are processed, so the live accumulator is
// 9 f32x2 (18 VGPR) instead of 27 (54). Finished g-planes scatter-store to the
// A-tile via 8 precomputed swizzled chunk pointers (ds_write_b16, offsets all
// compile-time). Rows are re-fetched across g (1.5x VMEM, L2/L3-hot) — traded
// for 2x occupancy. Waves 0/1 then run the 16x1024 @ 1024x32 MFMA GEMM.
__global__ __launch_bounds__(256, 4) void fused_kernel(const unsigned short* __restrict__ voxT,
                                                       const float* __restrict__ verts,
                                                       const unsigned short* __restrict__ Wp,
                                                       const float* __restrict__ bias,
                                                       float* __restrict__ out) {
    __shared__ unsigned short At[16 * AST];
    int tid = threadIdx.x;
    int vl = tid >> 4;               // 0..15 vertex in block
    int cp = tid & 15;               // channel pair: channels {2cp, 2cp+1}
    int vg = (int)blockIdx.x * 16 + vl;   // 3750*16 = 60000 exactly

    const float* vp = verts + (size_t)vg * 3;
    float vx = vp[0], vy = vp[1], vz = vp[2];
    const float sc = 2.0f / 95.0f;
    int wsx, wsy, wsz;
    float wx[3][4], wy[3][4];
    int dzt[3][2];
    float fzw[3][2];
    axis_setup(vx, sc, wsx, wx);           // x -> D axis (innermost spatial)
    axis_setup(vy, sc, wsy, wy);           // y -> W axis
    axis_setup_z(vz, sc, wsz, dzt, fzw);   // z -> H axis (2-tap form)
    int bb = (vg >= NV) ? 1 : 0;
    const unsigned short* vb = voxT + (size_t)bb * HWD * 32 + 2 * cp;

    // Swizzled chunk pointers: chunk kc of this lane's 64-short region lives at
    // slot (kc ^ (cp&7)) — matches the GEMM read side exactly.
    int e = cp & 7;
    unsigned short* lanebase = &At[vl * AST + cp * 64];
    unsigned short* bptr[8];
#pragma unroll
    for (int kc = 0; kc < 8; ++kc) bptr[kc] = lanebase + ((kc ^ e) << 3);

    // Zero the pad slots k=27..31 for both channels (W is zero there, but LDS
    // garbage could be NaN and NaN*0 = NaN).
#pragma unroll
    for (int chi = 0; chi < 2; ++chi) {
        unsigned short* p = bptr[chi * 4 + 3];
        p[3] = 0;
        *(unsigned long long*)(p + 4) = 0ull;   // shorts 4..7 (8B-aligned)
    }

    f32x2 zz = {0.f, 0.f};
#pragma unroll
    for (int g = 0; g < 3; ++g) {
        f32x2 fg[9];
#pragma unroll
        for (int i = 0; i < 9; ++i) fg[i] = zz;
#pragma unroll
        for (int t2 = 0; t2 < 2; ++t2) {
            int tz = dzt[g][t2];
            float wzv = fzw[g][t2];
            f32x2 ry[3][3];
#pragma unroll
            for (int bq = 0; bq < 3; ++bq)
#pragma unroll
                for (int a = 0; a < 3; ++a) ry[bq][a] = zz;
#pragma unroll
            for (int ty = 0; ty < 4; ++ty) {
                const unsigned short* row =
                    vb + (((size_t)(wsz + tz) * 96 + (size_t)(wsy + ty)) * 96 + wsx) * 32;
                unsigned int u0 = *(const unsigned int*)(row);
                unsigned int u1 = *(const unsigned int*)(row + 32);
                unsigned int u2 = *(const unsigned int*)(row + 64);
                unsigned int u3 = *(const unsigned int*)(row + 96);
                f32x2 b0 = up2(u0), b1 = up2(u1), b2 = up2(u2), b3 = up2(u3);
#pragma unroll
                for (int a = 0; a < 3; ++a) {
                    f32x2 r = b0 * wx[a][0] + b1 * wx[a][1] + b2 * wx[a][2] + b3 * wx[a][3];
#pragma unroll
                    for (int bq = 0; bq < 3; ++bq)
                        ry[bq][a] += r * wy[bq][ty];
                }
            }
#pragma unroll
            for (int bq = 0; bq < 3; ++bq)
#pragma unroll
                for (int a = 0; a < 3; ++a)
                    fg[3 * bq + a] += wzv * ry[bq][a];
        }
        // Scatter-store this g-plane: taps k = 9a+3b+g, both channels.
#pragma unroll
        for (int bq = 0; bq < 3; ++bq)
#pragma unroll
            for (int a = 0; a < 3; ++a) {
                int k1 = 9 * a + 3 * bq + g;           // compile-time
                f32x2 v = fg[3 * bq + a];
                bptr[k1 >> 3][k1 & 7] = bfc(v.x);      // channel 2cp
                bptr[4 + (k1 >> 3)][k1 & 7] = bfc(v.y);// channel 2cp+1
            }
    }

    __syncthreads();

    int wv = tid >> 6;               // wave id 0..3; waves 0,1 do the GEMM
    if (wv < 2) {
        int lane = tid & 63;
        int mrow = lane & 15, quad = lane >> 4;
        const bf16x8* wp = (const bf16x8*)Wp;
        f32x4 acc = {0.f, 0.f, 0.f, 0.f};
#pragma unroll 8
        for (int s = 0; s < 32; ++s) {
            // Global chunk G = s*4+quad; region cpg = G>>3, local k = G&7,
            // read at slot (k ^ (cpg&7)) to match the swizzled write.
            int cpg = s >> 1;
            int kk = ((s & 1) << 2) | quad;
            bf16x8 a = *(const bf16x8*)&At[mrow * AST + cpg * 64 + ((kk ^ (cpg & 7)) << 3)];
            bf16x8 b = wp[(s * 2 + wv) * 64 + lane];
            acc = __builtin_amdgcn_mfma_f32_16x16x32_bf16(a, b, acc, 0, 0, 0);
        }
        float bs = bias[wv * 16 + mrow];
#pragma unroll
        for (int r = 0; r < 4; ++r) {
            int v = (int)blockIdx.x * 16 + quad * 4 + r;
            out[(size_t)v * 32 + wv * 16 + mrow] = acc[r] + bs;
        }
    }
}

extern "C" void kernel_launch(void* const* d_in, const int* in_sizes, int n_in,
                              void* d_out, int out_size, void* d_ws, size_t ws_size,
                              hipStream_t stream) {
    const float* vox = (const float*)d_in[0];
    const float* verts = (const float*)d_in[1];
    const float* cw = (const float*)d_in[2];
    const float* cb = (const float*)d_in[3];
    float* out = (float*)d_out;

    // ws layout: Wp (64 KB) | voxT bf16 (2*HWD*32*2 = 113.25 MB). Total ~113.4 MB.
    unsigned short* Wp = (unsigned short*)d_ws;
    unsigned short* voxT = (unsigned short*)((char*)d_ws + 65536);

    hipLaunchKernelGGL(prep_kernel, dim3(128), dim3(256), 0, stream, cw, Wp);
    hipLaunchKernelGGL(transpose_kernel, dim3(9216), dim3(256), 0, stream, vox, voxT);
    hipLaunchKernelGGL(fused_kernel, dim3(3750), dim3(256), 0, stream,
                       voxT, verts, Wp, cb, out);
}